// Round 2
// baseline (396.841 us; speedup 1.0000x reference)
//
#include <hip/hip_runtime.h>
#include <math.h>

#define N_TOKENS 32768
#define N_EMBED  8192
#define EMB      32
#define DECAYF   0.99f
#define OMDF     0.01f

// ---- workspace layout (float-element offsets) ----
// zn lives in d_out's z_q region (written by k_prep, read by k_argmin/k_token,
// overwritten in-place by k_token) to keep ws usage small.
#define WS_WW    0                         // ||w||^2        [N_EMBED]
#define WS_ENC   (WS_WW + N_EMBED)         // indices (int)  [N_TOKENS]
#define WS_BINS  (WS_ENC + N_TOKENS)       // counts         [N_EMBED]
#define WS_ESUM  (WS_BINS + N_EMBED)       // scatter sum    [N_EMBED*EMB]
#define WS_LOSS  (WS_ESUM + N_EMBED*EMB)   // loss accum     [1]

// ---- output layout (float-element offsets), reference return order ----
#define OUT_ZQ   0
#define OUT_LOSS (N_TOKENS*EMB)            // 1048576
#define OUT_IDX  (OUT_LOSS + 1)            // 1048577
#define OUT_NW   (OUT_IDX + N_TOKENS)      // 1081345
#define OUT_CS   (OUT_NW + N_EMBED*EMB)    // 1343489

// ============ K1: normalize z rows; compute ||w||^2 per codebook row ============
__global__ void k_prep(const float* __restrict__ z, const float* __restrict__ w,
                       float* __restrict__ zn, float* __restrict__ ww) {
    int t = blockIdx.x * blockDim.x + threadIdx.x;
    if (t < N_TOKENS) {
        const float4* zp = (const float4*)(z + (size_t)t * EMB);
        float4 v[8];
        float acc = 0.f;
#pragma unroll
        for (int i = 0; i < 8; ++i) {
            v[i] = zp[i];
            acc += v[i].x * v[i].x + v[i].y * v[i].y + v[i].z * v[i].z + v[i].w * v[i].w;
        }
        float n = fmaxf(sqrtf(acc), 1e-12f);
        float4* o = (float4*)(zn + (size_t)t * EMB);
#pragma unroll
        for (int i = 0; i < 8; ++i) {
            float4 r;
            r.x = v[i].x / n; r.y = v[i].y / n; r.z = v[i].z / n; r.w = v[i].w / n;
            o[i] = r;
        }
    } else if (t < N_TOKENS + N_EMBED) {
        int r = t - N_TOKENS;
        const float4* wp = (const float4*)(w + (size_t)r * EMB);
        float acc = 0.f;
#pragma unroll
        for (int i = 0; i < 8; ++i) {
            float4 v = wp[i];
            acc += v.x * v.x + v.y * v.y + v.z * v.z + v.w * v.w;
        }
        ww[r] = acc;
    }
}

// ============ K2: fused distance + argmin ============
// Block = 512 threads = 8 waves; block owns 64 tokens (one per lane).
// Wave wv scans codebook slice [wv*1024, (wv+1)*1024); weight/ww addresses
// are wave-uniform (readfirstlane'd base + uniform i) -> scalar s_load path;
// z row lives in 32 VGPRs per lane. Key = ww[n] - 2*dot (zz is a per-token
// constant: dropping it preserves per-token argmin ordering).
#define SLICES 8
#define ROWS_PER_SLICE (N_EMBED / SLICES)   // 1024

__global__ __launch_bounds__(512) void k_argmin(const float* __restrict__ zn,
                                                const float* __restrict__ weight,
                                                const float* __restrict__ ww,
                                                int* __restrict__ enc) {
    __shared__ float sBest[SLICES][64];
    __shared__ int   sIdx[SLICES][64];

    const int lane = threadIdx.x & 63;
    const int wv   = __builtin_amdgcn_readfirstlane(threadIdx.x >> 6);
    const int token = blockIdx.x * 64 + lane;

    float zr[EMB];
    const float4* zp = (const float4*)(zn + (size_t)token * EMB);
#pragma unroll
    for (int i = 0; i < 8; ++i) {
        float4 v = zp[i];
        zr[4 * i + 0] = v.x; zr[4 * i + 1] = v.y; zr[4 * i + 2] = v.z; zr[4 * i + 3] = v.w;
    }

    const int n0 = wv * ROWS_PER_SLICE;
    const float* wrow  = weight + (size_t)n0 * EMB;
    const float* wwrow = ww + n0;

    float best = 3.4e38f;
    int bidx = 0;

#pragma unroll 4
    for (int i = 0; i < ROWS_PER_SLICE; ++i) {
        const float4* wp = (const float4*)(wrow + (size_t)i * EMB);
        float a0 = 0.f, a1 = 0.f;   // 2 chains: 4-cyc dep latency == issue rate
#pragma unroll
        for (int k = 0; k < 8; ++k) {
            float4 w4 = wp[k];
            a0 = fmaf(zr[4 * k + 0], w4.x, a0);
            a1 = fmaf(zr[4 * k + 1], w4.y, a1);
            a0 = fmaf(zr[4 * k + 2], w4.z, a0);
            a1 = fmaf(zr[4 * k + 3], w4.w, a1);
        }
        float key = fmaf(-2.f, a0 + a1, wwrow[i]);
        bool c = key < best;                // strict < keeps FIRST min (jnp.argmin)
        best = c ? key : best;
        bidx = c ? (n0 + i) : bidx;
    }

    sBest[wv][lane] = best;
    sIdx[wv][lane]  = bidx;
    __syncthreads();

    if (wv == 0) {
        float b = sBest[0][lane];
        int   bi = sIdx[0][lane];
#pragma unroll
        for (int s = 1; s < SLICES; ++s) {
            float ob = sBest[s][lane];
            int   oi = sIdx[s][lane];
            bool c = ob < b;               // ascending slices: ties keep lower index
            b  = c ? ob : b;
            bi = c ? oi : bi;
        }
        enc[token] = bi;
    }
}

// ============ K3: per-token outputs + scatters + loss ============
// Reads zn from out[OUT_ZQ] and overwrites it in place with z_q_st (each
// address is read before it is written, within the same thread).
__global__ void k_token(const float* __restrict__ weight,
                        const int* __restrict__ enc, float* __restrict__ out,
                        float* __restrict__ bins, float* __restrict__ esum,
                        float* __restrict__ loss) {
    int t = blockIdx.x * blockDim.x + threadIdx.x;
    int idx = enc[t];
    float4* zq = (float4*)(out + OUT_ZQ + (size_t)t * EMB);
    const float4* wp = (const float4*)(weight + (size_t)idx * EMB);

    float lacc = 0.f;
#pragma unroll
    for (int i = 0; i < 8; ++i) {
        float4 zv = zq[i];                 // normalized z (staged by k_prep)
        float4 wv = wp[i];
        float4 d, o;
        d.x = wv.x - zv.x; d.y = wv.y - zv.y; d.z = wv.z - zv.z; d.w = wv.w - zv.w;
        lacc += d.x * d.x + d.y * d.y + d.z * d.z + d.w * d.w;
        // straight-through: z + (z_q - z), replicating reference fp rounding
        o.x = zv.x + d.x; o.y = zv.y + d.y; o.z = zv.z + d.z; o.w = zv.w + d.w;
        zq[i] = o;
        atomicAdd(esum + (size_t)idx * EMB + 4 * i + 0, zv.x);
        atomicAdd(esum + (size_t)idx * EMB + 4 * i + 1, zv.y);
        atomicAdd(esum + (size_t)idx * EMB + 4 * i + 2, zv.z);
        atomicAdd(esum + (size_t)idx * EMB + 4 * i + 3, zv.w);
    }
    out[OUT_IDX + t] = (float)idx;
    atomicAdd(bins + idx, 1.0f);

    // wave-level loss reduction, one atomic per wave
#pragma unroll
    for (int off = 32; off > 0; off >>= 1) lacc += __shfl_xor(lacc, off, 64);
    if ((threadIdx.x & 63) == 0) atomicAdd(loss, lacc);
}

// ============ K4: EMA codebook update + finalize loss ============
__global__ void k_ema(const float* __restrict__ weight, const float* __restrict__ cs,
                      const float* __restrict__ bins, const float* __restrict__ esum,
                      const float* __restrict__ loss, float* __restrict__ out) {
    int n = blockIdx.x * blockDim.x + threadIdx.x;
    if (n == 0) {
        out[OUT_LOSS] = loss[0] * (1.0f / (float)(N_TOKENS * EMB));  // BETA = 1
    }
    if (n >= N_EMBED) return;

    float b = bins[n];
    out[OUT_CS + n] = cs[n] * DECAYF + b * OMDF;

    bool zero = (b == 0.0f);
    float safe = zero ? 1.0f : b;

    float w[EMB], en[EMB];
    const float* wrow = weight + (size_t)n * EMB;
    const float* erow = esum + (size_t)n * EMB;
    float nacc = 0.f;
#pragma unroll
    for (int i = 0; i < EMB; ++i) {
        w[i] = wrow[i];
        en[i] = erow[i] / safe;
        nacc += en[i] * en[i];
    }
    float nn = fmaxf(sqrtf(nacc), 1e-12f);
#pragma unroll
    for (int i = 0; i < EMB; ++i) {
        en[i] = zero ? w[i] : (en[i] / nn);
    }
    // new_weight = l2norm(w*decay + en*(1-decay))
    float acc2 = 0.f;
    float nw[EMB];
#pragma unroll
    for (int i = 0; i < EMB; ++i) {
        nw[i] = w[i] * DECAYF + en[i] * OMDF;
        acc2 += nw[i] * nw[i];
    }
    float n2 = fmaxf(sqrtf(acc2), 1e-12f);
#pragma unroll
    for (int i = 0; i < EMB; ++i) {
        out[OUT_NW + (size_t)n * EMB + i] = nw[i] / n2;
    }
}

// ============ launcher ============
extern "C" void kernel_launch(void* const* d_in, const int* in_sizes, int n_in,
                              void* d_out, int out_size, void* d_ws, size_t ws_size,
                              hipStream_t stream) {
    const float* z  = (const float*)d_in[0];
    const float* w  = (const float*)d_in[1];
    const float* cs = (const float*)d_in[2];
    float* out = (float*)d_out;
    float* ws  = (float*)d_ws;

    float* zn   = out + OUT_ZQ;          // staged normalized z (overwritten by k_token)
    float* ww   = ws + WS_WW;
    int*   enc  = (int*)(ws + WS_ENC);
    float* bins = ws + WS_BINS;
    float* esum = ws + WS_ESUM;
    float* loss = ws + WS_LOSS;

    // zero the accumulators (bins, esum, loss are contiguous)
    hipMemsetAsync(bins, 0, (size_t)(N_EMBED + N_EMBED * EMB + 1) * sizeof(float), stream);

    k_prep<<<(N_TOKENS + N_EMBED + 255) / 256, 256, 0, stream>>>(z, w, zn, ww);
    k_argmin<<<N_TOKENS / 64, 512, 0, stream>>>(zn, w, ww, enc);
    k_token<<<N_TOKENS / 256, 256, 0, stream>>>(w, enc, out, bins, esum, loss);
    k_ema<<<(N_EMBED + 255) / 256, 256, 0, stream>>>(w, cs, bins, esum, loss, out);
}

// Round 5
// 357.019 us; speedup vs baseline: 1.1115x; 1.1115x over previous
//
#include <hip/hip_runtime.h>
#include <math.h>

#define N_TOKENS 32768
#define N_EMBED  8192
#define EMB      32
#define DECAYF   0.99f
#define OMDF     0.01f

// ---- workspace layout (float-element offsets) ----
#define WS_WW    0                         // ||w||^2        [N_EMBED]
#define WS_ENC   (WS_WW + N_EMBED)         // indices (int)  [N_TOKENS]
#define WS_BINS  (WS_ENC + N_TOKENS)       // counts         [N_EMBED]
#define WS_ESUM  (WS_BINS + N_EMBED)       // scatter sum    [N_EMBED*EMB]
#define WS_LOSS  (WS_ESUM + N_EMBED*EMB)   // loss accum     [1]

// ---- output layout (float-element offsets), reference return order ----
#define OUT_ZQ   0
#define OUT_LOSS (N_TOKENS*EMB)            // 1048576
#define OUT_IDX  (OUT_LOSS + 1)            // 1048577
#define OUT_NW   (OUT_IDX + N_TOKENS)      // 1081345
#define OUT_CS   (OUT_NW + N_EMBED*EMB)    // 1343489

// ============ K0: ||w||^2 per codebook row ============
__global__ void k_ww(const float* __restrict__ w, float* __restrict__ ww) {
    int r = blockIdx.x * blockDim.x + threadIdx.x;
    if (r >= N_EMBED) return;
    const float4* wp = (const float4*)(w + (size_t)r * EMB);
    float acc = 0.f;
#pragma unroll
    for (int i = 0; i < 8; ++i) {
        float4 v = wp[i];
        acc += v.x * v.x + v.y * v.y + v.z * v.z + v.w * v.w;
    }
    ww[r] = acc;
}

// ============ K1: fused normalize + distance + argmin ============
// Block = 1024 threads = 16 waves; block owns 128 tokens (2 per lane, T=2).
// Every wave holds the SAME 128 tokens in registers; wave wv scans codebook
// slice [wv*512, (wv+1)*512). Weight/ww addresses are wave-uniform -> scalar
// s_load path (SGPR broadcast operand into v_fma). Key = ww[n] - 2*dot
// (per-token constant zz dropped: ordering preserved).
#define SLICES 16
#define ROWS_PER_SLICE (N_EMBED / SLICES)   // 512
#define TOK_PER_BLOCK  128

__global__ __launch_bounds__(1024, 4) void k_argmin(
        const float* __restrict__ z, const float* __restrict__ weight,
        const float* __restrict__ ww, int* __restrict__ enc,
        float* __restrict__ zn) {
    __shared__ float sBest[SLICES][2][64];
    __shared__ int   sIdx[SLICES][2][64];

    const int lane = threadIdx.x & 63;
    const int wv   = __builtin_amdgcn_readfirstlane(threadIdx.x >> 6);
    const int tok0 = blockIdx.x * TOK_PER_BLOCK + lane;        // token for t=0
    const int tok1 = tok0 + 64;                                // token for t=1

    // --- load + normalize both token rows (redundant per wave; ~1% of loop cost)
    float zr0[EMB], zr1[EMB];
    {
        const float4* zp0 = (const float4*)(z + (size_t)tok0 * EMB);
        const float4* zp1 = (const float4*)(z + (size_t)tok1 * EMB);
        float acc0 = 0.f, acc1 = 0.f;
#pragma unroll
        for (int i = 0; i < 8; ++i) {
            float4 v0 = zp0[i];
            float4 v1 = zp1[i];
            acc0 += v0.x * v0.x + v0.y * v0.y + v0.z * v0.z + v0.w * v0.w;
            acc1 += v1.x * v1.x + v1.y * v1.y + v1.z * v1.z + v1.w * v1.w;
            zr0[4*i+0] = v0.x; zr0[4*i+1] = v0.y; zr0[4*i+2] = v0.z; zr0[4*i+3] = v0.w;
            zr1[4*i+0] = v1.x; zr1[4*i+1] = v1.y; zr1[4*i+2] = v1.z; zr1[4*i+3] = v1.w;
        }
        float n0 = fmaxf(sqrtf(acc0), 1e-12f);
        float n1 = fmaxf(sqrtf(acc1), 1e-12f);
#pragma unroll
        for (int k = 0; k < EMB; ++k) { zr0[k] = zr0[k] / n0; zr1[k] = zr1[k] / n1; }
    }
    // Pin the normalized rows into VGPRs: values become opaque asm outputs, so
    // the backend cannot rematerialize them via global reloads (r2: VGPR=28
    // showed exactly that pathology).
#pragma unroll
    for (int k = 0; k < EMB; ++k) {
        asm volatile("" : "+v"(zr0[k]));
        asm volatile("" : "+v"(zr1[k]));
    }

    // wave 0 persists normalized z for k_token (out z_q region)
    if (wv == 0) {
        float4* o0 = (float4*)(zn + (size_t)tok0 * EMB);
        float4* o1 = (float4*)(zn + (size_t)tok1 * EMB);
#pragma unroll
        for (int i = 0; i < 8; ++i) {
            float4 a, b;
            a.x = zr0[4*i+0]; a.y = zr0[4*i+1]; a.z = zr0[4*i+2]; a.w = zr0[4*i+3];
            b.x = zr1[4*i+0]; b.y = zr1[4*i+1]; b.z = zr1[4*i+2]; b.w = zr1[4*i+3];
            o0[i] = a; o1[i] = b;
        }
    }

    const int n0r = wv * ROWS_PER_SLICE;
    const float* wrow  = weight + (size_t)n0r * EMB;
    const float* wwrow = ww + n0r;

    float best0 = 3.4e38f, best1 = 3.4e38f;
    int bidx0 = 0, bidx1 = 0;

#pragma unroll 4
    for (int i = 0; i < ROWS_PER_SLICE; ++i) {
        const float4* wp = (const float4*)(wrow + (size_t)i * EMB);
        float a00 = 0.f, a01 = 0.f, a10 = 0.f, a11 = 0.f;   // 2 chains per token
#pragma unroll
        for (int k = 0; k < 8; ++k) {
            float4 w4 = wp[k];
            a00 = fmaf(zr0[4*k+0], w4.x, a00);
            a01 = fmaf(zr0[4*k+1], w4.y, a01);
            a10 = fmaf(zr1[4*k+0], w4.x, a10);
            a11 = fmaf(zr1[4*k+1], w4.y, a11);
            a00 = fmaf(zr0[4*k+2], w4.z, a00);
            a01 = fmaf(zr0[4*k+3], w4.w, a01);
            a10 = fmaf(zr1[4*k+2], w4.z, a10);
            a11 = fmaf(zr1[4*k+3], w4.w, a11);
        }
        float wwv = wwrow[i];
        float key0 = fmaf(-2.f, a00 + a01, wwv);
        float key1 = fmaf(-2.f, a10 + a11, wwv);
        bool c0 = key0 < best0;            // strict < keeps FIRST min (jnp.argmin)
        bool c1 = key1 < best1;
        best0 = c0 ? key0 : best0;  bidx0 = c0 ? (n0r + i) : bidx0;
        best1 = c1 ? key1 : best1;  bidx1 = c1 ? (n0r + i) : bidx1;
    }

    sBest[wv][0][lane] = best0;  sIdx[wv][0][lane] = bidx0;
    sBest[wv][1][lane] = best1;  sIdx[wv][1][lane] = bidx1;
    __syncthreads();

    if (threadIdx.x < 2 * 64) {
        const int l = threadIdx.x & 63;
        const int t = threadIdx.x >> 6;
        float b = sBest[0][t][l];
        int   bi = sIdx[0][t][l];
#pragma unroll
        for (int s = 1; s < SLICES; ++s) {
            float ob = sBest[s][t][l];
            int   oi = sIdx[s][t][l];
            bool c = ob < b;               // ascending slices: ties keep lower index
            b  = c ? ob : b;
            bi = c ? oi : bi;
        }
        enc[blockIdx.x * TOK_PER_BLOCK + t * 64 + l] = bi;
    }
}

// ============ K3: per-token outputs + scatters + loss ============
// Reads zn from out[OUT_ZQ] and overwrites it in place with z_q_st (each
// address is read before written, within the same thread).
__global__ void k_token(const float* __restrict__ weight,
                        const int* __restrict__ enc, float* __restrict__ out,
                        float* __restrict__ bins, float* __restrict__ esum,
                        float* __restrict__ loss) {
    int t = blockIdx.x * blockDim.x + threadIdx.x;
    int idx = enc[t];
    float4* zq = (float4*)(out + OUT_ZQ + (size_t)t * EMB);
    const float4* wp = (const float4*)(weight + (size_t)idx * EMB);

    float lacc = 0.f;
#pragma unroll
    for (int i = 0; i < 8; ++i) {
        float4 zv = zq[i];                 // normalized z (staged by k_argmin)
        float4 wv = wp[i];
        float4 d, o;
        d.x = wv.x - zv.x; d.y = wv.y - zv.y; d.z = wv.z - zv.z; d.w = wv.w - zv.w;
        lacc += d.x * d.x + d.y * d.y + d.z * d.z + d.w * d.w;
        // straight-through: z + (z_q - z), replicating reference fp rounding
        o.x = zv.x + d.x; o.y = zv.y + d.y; o.z = zv.z + d.z; o.w = zv.w + d.w;
        zq[i] = o;
        atomicAdd(esum + (size_t)idx * EMB + 4 * i + 0, zv.x);
        atomicAdd(esum + (size_t)idx * EMB + 4 * i + 1, zv.y);
        atomicAdd(esum + (size_t)idx * EMB + 4 * i + 2, zv.z);
        atomicAdd(esum + (size_t)idx * EMB + 4 * i + 3, zv.w);
    }
    out[OUT_IDX + t] = (float)idx;
    atomicAdd(bins + idx, 1.0f);

    // wave-level loss reduction, one atomic per wave
#pragma unroll
    for (int off = 32; off > 0; off >>= 1) lacc += __shfl_xor(lacc, off, 64);
    if ((threadIdx.x & 63) == 0) atomicAdd(loss, lacc);
}

// ============ K4: EMA codebook update + finalize loss ============
__global__ void k_ema(const float* __restrict__ weight, const float* __restrict__ cs,
                      const float* __restrict__ bins, const float* __restrict__ esum,
                      const float* __restrict__ loss, float* __restrict__ out) {
    int n = blockIdx.x * blockDim.x + threadIdx.x;
    if (n == 0) {
        out[OUT_LOSS] = loss[0] * (1.0f / (float)(N_TOKENS * EMB));  // BETA = 1
    }
    if (n >= N_EMBED) return;

    float b = bins[n];
    out[OUT_CS + n] = cs[n] * DECAYF + b * OMDF;

    bool zero = (b == 0.0f);
    float safe = zero ? 1.0f : b;

    float w[EMB], en[EMB];
    const float* wrow = weight + (size_t)n * EMB;
    const float* erow = esum + (size_t)n * EMB;
    float nacc = 0.f;
#pragma unroll
    for (int i = 0; i < EMB; ++i) {
        w[i] = wrow[i];
        en[i] = erow[i] / safe;
        nacc += en[i] * en[i];
    }
    float nn = fmaxf(sqrtf(nacc), 1e-12f);
#pragma unroll
    for (int i = 0; i < EMB; ++i) {
        en[i] = zero ? w[i] : (en[i] / nn);
    }
    float acc2 = 0.f;
    float nw[EMB];
#pragma unroll
    for (int i = 0; i < EMB; ++i) {
        nw[i] = w[i] * DECAYF + en[i] * OMDF;
        acc2 += nw[i] * nw[i];
    }
    float n2 = fmaxf(sqrtf(acc2), 1e-12f);
#pragma unroll
    for (int i = 0; i < EMB; ++i) {
        out[OUT_NW + (size_t)n * EMB + i] = nw[i] / n2;
    }
}

// ============ launcher ============
extern "C" void kernel_launch(void* const* d_in, const int* in_sizes, int n_in,
                              void* d_out, int out_size, void* d_ws, size_t ws_size,
                              hipStream_t stream) {
    const float* z  = (const float*)d_in[0];
    const float* w  = (const float*)d_in[1];
    const float* cs = (const float*)d_in[2];
    float* out = (float*)d_out;
    float* ws  = (float*)d_ws;

    float* zn   = out + OUT_ZQ;          // staged normalized z (overwritten by k_token)
    float* ww   = ws + WS_WW;
    int*   enc  = (int*)(ws + WS_ENC);
    float* bins = ws + WS_BINS;
    float* esum = ws + WS_ESUM;
    float* loss = ws + WS_LOSS;

    // zero the accumulators (bins, esum, loss are contiguous)
    hipMemsetAsync(bins, 0, (size_t)(N_EMBED + N_EMBED * EMB + 1) * sizeof(float), stream);

    k_ww<<<N_EMBED / 256, 256, 0, stream>>>(w, ww);
    k_argmin<<<N_TOKENS / TOK_PER_BLOCK, 1024, 0, stream>>>(z, w, ww, enc, zn);
    k_token<<<N_TOKENS / 256, 256, 0, stream>>>(w, enc, out, bins, esum, loss);
    k_ema<<<(N_EMBED + 255) / 256, 256, 0, stream>>>(w, cs, bins, esum, loss, out);
}

// Round 6
// 343.513 us; speedup vs baseline: 1.1552x; 1.0393x over previous
//
#include <hip/hip_runtime.h>
#include <math.h>

#define N_TOKENS 32768
#define N_EMBED  8192
#define EMB      32
#define DECAYF   0.99f
#define OMDF     0.01f

// ---- workspace layout (float-element offsets) ----
#define WS_WW    0                         // ||w||^2        [N_EMBED]
#define WS_ENC   (WS_WW + N_EMBED)         // indices (int)  [N_TOKENS]
#define WS_BINS  (WS_ENC + N_TOKENS)       // counts         [N_EMBED]
#define WS_ESUM  (WS_BINS + N_EMBED)       // scatter sum    [N_EMBED*EMB]
#define WS_LOSS  (WS_ESUM + N_EMBED*EMB)   // loss accum     [1]

// ---- output layout (float-element offsets), reference return order ----
#define OUT_ZQ   0
#define OUT_LOSS (N_TOKENS*EMB)            // 1048576
#define OUT_IDX  (OUT_LOSS + 1)            // 1048577
#define OUT_NW   (OUT_IDX + N_TOKENS)      // 1081345
#define OUT_CS   (OUT_NW + N_EMBED*EMB)    // 1343489

// ============ K0: ||w||^2 per codebook row ============
__global__ void k_ww(const float* __restrict__ w, float* __restrict__ ww) {
    int r = blockIdx.x * blockDim.x + threadIdx.x;
    if (r >= N_EMBED) return;
    const float4* wp = (const float4*)(w + (size_t)r * EMB);
    float acc = 0.f;
#pragma unroll
    for (int i = 0; i < 8; ++i) {
        float4 v = wp[i];
        acc += v.x * v.x + v.y * v.y + v.z * v.z + v.w * v.w;
    }
    ww[r] = acc;
}

// ============ K1: fused normalize + distance + argmin ============
// Block = 1024 threads = 16 waves; block owns 128 tokens (2 per lane, T=2).
// Every wave holds the SAME 128 tokens in registers; wave wv scans codebook
// slice [wv*512, (wv+1)*512). Weight/ww addresses are wave-uniform -> scalar
// s_load path (SGPR broadcast operand into v_fma). Key = ww[n] - 2*dot
// (per-token constant zz dropped: ordering preserved).
//
// amdgpu_waves_per_eu(4,4): r5 showed the allocator targeting 8 waves/EU
// (2x 16-wave blocks/CU) -> 64-VGPR budget -> refused the 64-float register
// tile (VGPR_Count=40, z-row traffic stalls, VALUBusy 63%). Pinning waves/EU
// to exactly 4 sets the budget to 128 VGPRs; grid = 256 blocks = 1 block/CU.
#define SLICES 16
#define ROWS_PER_SLICE (N_EMBED / SLICES)   // 512
#define TOK_PER_BLOCK  128

__global__ __attribute__((amdgpu_waves_per_eu(4, 4))) __launch_bounds__(1024)
void k_argmin(
        const float* __restrict__ z, const float* __restrict__ weight,
        const float* __restrict__ ww, int* __restrict__ enc,
        float* __restrict__ zn) {
    __shared__ float sBest[SLICES][2][64];
    __shared__ int   sIdx[SLICES][2][64];

    const int lane = threadIdx.x & 63;
    const int wv   = __builtin_amdgcn_readfirstlane(threadIdx.x >> 6);
    const int tok0 = blockIdx.x * TOK_PER_BLOCK + lane;        // token for t=0
    const int tok1 = tok0 + 64;                                // token for t=1

    // --- load + normalize both token rows (redundant per wave; ~1% of loop cost)
    float zr0[EMB], zr1[EMB];
    {
        const float4* zp0 = (const float4*)(z + (size_t)tok0 * EMB);
        const float4* zp1 = (const float4*)(z + (size_t)tok1 * EMB);
        float acc0 = 0.f, acc1 = 0.f;
#pragma unroll
        for (int i = 0; i < 8; ++i) {
            float4 v0 = zp0[i];
            float4 v1 = zp1[i];
            acc0 += v0.x * v0.x + v0.y * v0.y + v0.z * v0.z + v0.w * v0.w;
            acc1 += v1.x * v1.x + v1.y * v1.y + v1.z * v1.z + v1.w * v1.w;
            zr0[4*i+0] = v0.x; zr0[4*i+1] = v0.y; zr0[4*i+2] = v0.z; zr0[4*i+3] = v0.w;
            zr1[4*i+0] = v1.x; zr1[4*i+1] = v1.y; zr1[4*i+2] = v1.z; zr1[4*i+3] = v1.w;
        }
        float n0 = fmaxf(sqrtf(acc0), 1e-12f);
        float n1 = fmaxf(sqrtf(acc1), 1e-12f);
#pragma unroll
        for (int k = 0; k < EMB; ++k) { zr0[k] = zr0[k] / n0; zr1[k] = zr1[k] / n1; }
    }
    // Pin the normalized rows into VGPRs: values become opaque asm outputs, so
    // the backend cannot rematerialize them via global reloads.
#pragma unroll
    for (int k = 0; k < EMB; ++k) {
        asm volatile("" : "+v"(zr0[k]));
        asm volatile("" : "+v"(zr1[k]));
    }

    // wave 0 persists normalized z for k_token (out z_q region)
    if (wv == 0) {
        float4* o0 = (float4*)(zn + (size_t)tok0 * EMB);
        float4* o1 = (float4*)(zn + (size_t)tok1 * EMB);
#pragma unroll
        for (int i = 0; i < 8; ++i) {
            float4 a, b;
            a.x = zr0[4*i+0]; a.y = zr0[4*i+1]; a.z = zr0[4*i+2]; a.w = zr0[4*i+3];
            b.x = zr1[4*i+0]; b.y = zr1[4*i+1]; b.z = zr1[4*i+2]; b.w = zr1[4*i+3];
            o0[i] = a; o1[i] = b;
        }
    }

    const int n0r = wv * ROWS_PER_SLICE;
    const float* wrow  = weight + (size_t)n0r * EMB;
    const float* wwrow = ww + n0r;

    float best0 = 3.4e38f, best1 = 3.4e38f;
    int bidx0 = 0, bidx1 = 0;

#pragma unroll 4
    for (int i = 0; i < ROWS_PER_SLICE; ++i) {
        const float4* wp = (const float4*)(wrow + (size_t)i * EMB);
        float a00 = 0.f, a01 = 0.f, a10 = 0.f, a11 = 0.f;   // 2 chains per token
#pragma unroll
        for (int k = 0; k < 8; ++k) {
            float4 w4 = wp[k];
            a00 = fmaf(zr0[4*k+0], w4.x, a00);
            a01 = fmaf(zr0[4*k+1], w4.y, a01);
            a10 = fmaf(zr1[4*k+0], w4.x, a10);
            a11 = fmaf(zr1[4*k+1], w4.y, a11);
            a00 = fmaf(zr0[4*k+2], w4.z, a00);
            a01 = fmaf(zr0[4*k+3], w4.w, a01);
            a10 = fmaf(zr1[4*k+2], w4.z, a10);
            a11 = fmaf(zr1[4*k+3], w4.w, a11);
        }
        float wwv = wwrow[i];
        float key0 = fmaf(-2.f, a00 + a01, wwv);
        float key1 = fmaf(-2.f, a10 + a11, wwv);
        bool c0 = key0 < best0;            // strict < keeps FIRST min (jnp.argmin)
        bool c1 = key1 < best1;
        best0 = c0 ? key0 : best0;  bidx0 = c0 ? (n0r + i) : bidx0;
        best1 = c1 ? key1 : best1;  bidx1 = c1 ? (n0r + i) : bidx1;
    }

    sBest[wv][0][lane] = best0;  sIdx[wv][0][lane] = bidx0;
    sBest[wv][1][lane] = best1;  sIdx[wv][1][lane] = bidx1;
    __syncthreads();

    if (threadIdx.x < 2 * 64) {
        const int l = threadIdx.x & 63;
        const int t = threadIdx.x >> 6;
        float b = sBest[0][t][l];
        int   bi = sIdx[0][t][l];
#pragma unroll
        for (int s = 1; s < SLICES; ++s) {
            float ob = sBest[s][t][l];
            int   oi = sIdx[s][t][l];
            bool c = ob < b;               // ascending slices: ties keep lower index
            b  = c ? ob : b;
            bi = c ? oi : bi;
        }
        enc[blockIdx.x * TOK_PER_BLOCK + t * 64 + l] = bi;
    }
}

// ============ K3: per-token outputs + scatters + loss ============
// Reads zn from out[OUT_ZQ] and overwrites it in place with z_q_st (each
// address is read before written, within the same thread).
__global__ void k_token(const float* __restrict__ weight,
                        const int* __restrict__ enc, float* __restrict__ out,
                        float* __restrict__ bins, float* __restrict__ esum,
                        float* __restrict__ loss) {
    int t = blockIdx.x * blockDim.x + threadIdx.x;
    int idx = enc[t];
    float4* zq = (float4*)(out + OUT_ZQ + (size_t)t * EMB);
    const float4* wp = (const float4*)(weight + (size_t)idx * EMB);

    float lacc = 0.f;
#pragma unroll
    for (int i = 0; i < 8; ++i) {
        float4 zv = zq[i];                 // normalized z (staged by k_argmin)
        float4 wv = wp[i];
        float4 d, o;
        d.x = wv.x - zv.x; d.y = wv.y - zv.y; d.z = wv.z - zv.z; d.w = wv.w - zv.w;
        lacc += d.x * d.x + d.y * d.y + d.z * d.z + d.w * d.w;
        // straight-through: z + (z_q - z), replicating reference fp rounding
        o.x = zv.x + d.x; o.y = zv.y + d.y; o.z = zv.z + d.z; o.w = zv.w + d.w;
        zq[i] = o;
        atomicAdd(esum + (size_t)idx * EMB + 4 * i + 0, zv.x);
        atomicAdd(esum + (size_t)idx * EMB + 4 * i + 1, zv.y);
        atomicAdd(esum + (size_t)idx * EMB + 4 * i + 2, zv.z);
        atomicAdd(esum + (size_t)idx * EMB + 4 * i + 3, zv.w);
    }
    out[OUT_IDX + t] = (float)idx;
    atomicAdd(bins + idx, 1.0f);

    // wave-level loss reduction, one atomic per wave
#pragma unroll
    for (int off = 32; off > 0; off >>= 1) lacc += __shfl_xor(lacc, off, 64);
    if ((threadIdx.x & 63) == 0) atomicAdd(loss, lacc);
}

// ============ K4: EMA codebook update + finalize loss ============
__global__ void k_ema(const float* __restrict__ weight, const float* __restrict__ cs,
                      const float* __restrict__ bins, const float* __restrict__ esum,
                      const float* __restrict__ loss, float* __restrict__ out) {
    int n = blockIdx.x * blockDim.x + threadIdx.x;
    if (n == 0) {
        out[OUT_LOSS] = loss[0] * (1.0f / (float)(N_TOKENS * EMB));  // BETA = 1
    }
    if (n >= N_EMBED) return;

    float b = bins[n];
    out[OUT_CS + n] = cs[n] * DECAYF + b * OMDF;

    bool zero = (b == 0.0f);
    float safe = zero ? 1.0f : b;

    float w[EMB], en[EMB];
    const float* wrow = weight + (size_t)n * EMB;
    const float* erow = esum + (size_t)n * EMB;
    float nacc = 0.f;
#pragma unroll
    for (int i = 0; i < EMB; ++i) {
        w[i] = wrow[i];
        en[i] = erow[i] / safe;
        nacc += en[i] * en[i];
    }
    float nn = fmaxf(sqrtf(nacc), 1e-12f);
#pragma unroll
    for (int i = 0; i < EMB; ++i) {
        en[i] = zero ? w[i] : (en[i] / nn);
    }
    float acc2 = 0.f;
    float nw[EMB];
#pragma unroll
    for (int i = 0; i < EMB; ++i) {
        nw[i] = w[i] * DECAYF + en[i] * OMDF;
        acc2 += nw[i] * nw[i];
    }
    float n2 = fmaxf(sqrtf(acc2), 1e-12f);
#pragma unroll
    for (int i = 0; i < EMB; ++i) {
        out[OUT_NW + (size_t)n * EMB + i] = nw[i] / n2;
    }
}

// ============ launcher ============
extern "C" void kernel_launch(void* const* d_in, const int* in_sizes, int n_in,
                              void* d_out, int out_size, void* d_ws, size_t ws_size,
                              hipStream_t stream) {
    const float* z  = (const float*)d_in[0];
    const float* w  = (const float*)d_in[1];
    const float* cs = (const float*)d_in[2];
    float* out = (float*)d_out;
    float* ws  = (float*)d_ws;

    float* zn   = out + OUT_ZQ;          // staged normalized z (overwritten by k_token)
    float* ww   = ws + WS_WW;
    int*   enc  = (int*)(ws + WS_ENC);
    float* bins = ws + WS_BINS;
    float* esum = ws + WS_ESUM;
    float* loss = ws + WS_LOSS;

    // zero the accumulators (bins, esum, loss are contiguous)
    hipMemsetAsync(bins, 0, (size_t)(N_EMBED + N_EMBED * EMB + 1) * sizeof(float), stream);

    k_ww<<<N_EMBED / 256, 256, 0, stream>>>(w, ww);
    k_argmin<<<N_TOKENS / TOK_PER_BLOCK, 1024, 0, stream>>>(z, w, ww, enc, zn);
    k_token<<<N_TOKENS / 256, 256, 0, stream>>>(w, enc, out, bins, esum, loss);
    k_ema<<<(N_EMBED + 255) / 256, 256, 0, stream>>>(w, cs, bins, esum, loss, out);
}